// Round 7
// baseline (19.709 us; speedup 1.0000x reference)
//
#include <hip/hip_runtime.h>
#include <math.h>

#define Gg 64
#define Ll 4096
#define Ss 65536
#define Nn (Gg * Ll)                      // 262144 rows
#define PB 1024                           // pair-block threads
#define CHUNKS 8                          // blocks per group
#define PAIR_BLOCKS (Gg * CHUNKS)         // 512
#define PPB (Ss / CHUNKS)                 // 8192 pairs per block (8/thread)
#define BLOCK 256

// fallback path constants
#define K_CHUNKS 32
#define DIR_BLOCKS (Gg * K_CHUNKS)
#define DIR_PAIRS (Ss / K_CHUNKS)

typedef _Float16 h2 __attribute__((ext_vector_type(2)));
typedef _Float16 h8 __attribute__((ext_vector_type(8)));

struct f3 { float x, y, z; };             // align 4, size 12 -> dwordx3 load

__device__ inline float dot2f16(h2 a, h2 b, float c) {
#if __has_builtin(__builtin_amdgcn_fdot2)
  return __builtin_amdgcn_fdot2(a, b, c, false);
#else
  return fmaf((float)a[0], (float)b[0], fmaf((float)a[1], (float)b[1], c));
#endif
}

// gather one pair from the LDS tile
#define PAIR_STEP(LI, RI)                                        \
  do {                                                           \
    h8 Lv = tile[(LI) & (Ll - 1)];                               \
    h8 Rv = tile[(RI) & (Ll - 1)];                               \
    h8 Dv = Lv - Rv;                                             \
    h2 d01 = __builtin_shufflevector(Dv, Dv, 0, 1);              \
    h2 d23 = __builtin_shufflevector(Dv, Dv, 2, 3);              \
    float dzi = (float)Dv[4];                                    \
    float dzt = (float)Dv[5];                                    \
    float din2 = dot2f16(d01, d01, dzi * dzi);                   \
    float dtg2 = dot2f16(d23, d23, dzt * dzt);                   \
    float dd = sqrtf(din2) - sqrtf(dtg2);                        \
    facc = fmaf(dd, dd, facc);                                   \
  } while (0)

// ---------------------------------------------------------------------------
// Fused kernel (int32 indices).
// Phase 1 (stage): ONLY the strided CA reads -> fp16 tile in LDS. The barrier
//   drain then covers just 18.9MB of HBM (TA-bound ~3.8us/CU), not the index
//   stream.
// Phase 2 (gather): index loads issued POST-barrier, 2-deep int4 pipeline.
//   The 33.5MB index HBM stream flows concurrently with the DS-pipe gather
//   (different pipes; 32 waves/CU hide the load latency). Compiler's counted
//   vmcnt lets batch-0 math start while batch-1 is in flight.
// __launch_bounds__(PB,8): VGPR<=64 so 2 blocks/CU (32 waves) co-reside.
// ---------------------------------------------------------------------------
__global__ __launch_bounds__(PB, 8) void fused_kernel(
    const float* __restrict__ inp, const float* __restrict__ tgt,
    const int* __restrict__ left, const int* __restrict__ right,
    float* __restrict__ partial) {
  __shared__ h8 tile[Ll];   // 64 KB

  int bid = blockIdx.x;
  int xcd = bid & 7;
  int j = bid >> 3;
  int group = xcd * 8 + (j & 7);  // all 8 chunk-blocks of a group on one XCD
  int chunk = j >> 3;
  int tid = threadIdx.x;

  // ---- phase 1: stage + compact, 4 rows per thread ----
  const float* ib = inp + (size_t)group * Ll * 9 + 3;  // CA atom base
  const float* tb = tgt + (size_t)group * Ll * 9 + 3;
#pragma unroll
  for (int q = 0; q < 4; ++q) {
    int row = q * PB + tid;
    f3 a = *(const f3*)(ib + (size_t)row * 9);
    f3 b = *(const f3*)(tb + (size_t)row * 9);
    h8 r;
    r[0] = (_Float16)a.x;
    r[1] = (_Float16)a.y;
    r[2] = (_Float16)b.x;
    r[3] = (_Float16)b.y;
    r[4] = (_Float16)a.z;
    r[5] = (_Float16)b.z;
    r[6] = (_Float16)0.f;
    r[7] = (_Float16)0.f;
    tile[row] = r;
  }
  __syncthreads();

  // ---- phase 2: pipelined index load + LDS gather ----
  size_t base = (size_t)group * Ss + (size_t)chunk * PPB;
  const int4* lp = (const int4*)(left + base);
  const int4* rp = (const int4*)(right + base);

  // issue order L0,R0,L1,R1: counted vmcnt lets L0/R0 math start while
  // L1/R1 are still outstanding.
  int4 L0 = lp[tid];
  int4 R0 = rp[tid];
  int4 L1 = lp[PB + tid];
  int4 R1 = rp[PB + tid];

  float facc = 0.f;
  PAIR_STEP(L0.x, R0.x);
  PAIR_STEP(L0.y, R0.y);
  PAIR_STEP(L0.z, R0.z);
  PAIR_STEP(L0.w, R0.w);
  PAIR_STEP(L1.x, R1.x);
  PAIR_STEP(L1.y, R1.y);
  PAIR_STEP(L1.z, R1.z);
  PAIR_STEP(L1.w, R1.w);

  // ---- block reduce -> partial ----
  for (int off = 32; off; off >>= 1) facc += __shfl_down(facc, off, 64);
  __shared__ float wsum[PB / 64];
  int lane = tid & 63;
  int wave = tid >> 6;
  if (lane == 0) wsum[wave] = facc;
  __syncthreads();
  if (tid == 0) {
    float s = 0.f;
    for (int w = 0; w < PB / 64; ++w) s += wsum[w];
    partial[bid] = s;
  }
}

// ---------------------------------------------------------------------------
// Fallback (int64 indices or tiny workspace): direct f32 gathers.
// ---------------------------------------------------------------------------
template <typename IT>
__global__ __launch_bounds__(BLOCK) void pair_kernel_direct(
    const float* __restrict__ inp, const float* __restrict__ tgt,
    const IT* __restrict__ left, const IT* __restrict__ right,
    float* __restrict__ partial) {
  int bid = blockIdx.x;
  int x = bid & 7;
  int j = bid >> 3;
  int group = x + 8 * (j / K_CHUNKS);
  int chunk = j % K_CHUNKS;
  size_t base = (size_t)group * Ss + (size_t)chunk * DIR_PAIRS;

  float acc = 0.f;
  for (int t = threadIdx.x; t < DIR_PAIRS; t += BLOCK) {
    size_t p = base + t;
    size_t li = (size_t)left[p] * 9 + 3;
    size_t ri = (size_t)right[p] * 9 + 3;
    float dx = inp[li + 0] - inp[ri + 0];
    float dy = inp[li + 1] - inp[ri + 1];
    float dz = inp[li + 2] - inp[ri + 2];
    float tx = tgt[li + 0] - tgt[ri + 0];
    float ty = tgt[li + 1] - tgt[ri + 1];
    float tz = tgt[li + 2] - tgt[ri + 2];
    float din = sqrtf(dx * dx + dy * dy + dz * dz);
    float dtg = sqrtf(tx * tx + ty * ty + tz * tz);
    float d = din - dtg;
    acc += d * d;
  }
  for (int off = 32; off; off >>= 1) acc += __shfl_down(acc, off, 64);
  __shared__ float wsum[BLOCK / 64];
  if ((threadIdx.x & 63) == 0) wsum[threadIdx.x >> 6] = acc;
  __syncthreads();
  if (threadIdx.x == 0) {
    float s = 0.f;
    for (int w = 0; w < BLOCK / 64; ++w) s += wsum[w];
    partial[bid] = s;
  }
}

// ---------------------------------------------------------------------------
// Final reduce: deterministic fixed-order fp64 sum of block partials.
// ---------------------------------------------------------------------------
__global__ __launch_bounds__(BLOCK) void reduce_kernel(
    const float* __restrict__ partial, int n, float* __restrict__ out) {
  double acc = 0.0;
  for (int i = threadIdx.x; i < n; i += BLOCK) acc += (double)partial[i];
  for (int off = 32; off; off >>= 1) acc += __shfl_down(acc, off, 64);
  __shared__ double wsum[BLOCK / 64];
  if ((threadIdx.x & 63) == 0) wsum[threadIdx.x >> 6] = acc;
  __syncthreads();
  if (threadIdx.x == 0) {
    double s = 0.0;
    for (int w = 0; w < BLOCK / 64; ++w) s += wsum[w];
    out[0] = (float)(s / (double)((size_t)Gg * Ss));
  }
}

extern "C" void kernel_launch(void* const* d_in, const int* in_sizes, int n_in,
                              void* d_out, int out_size, void* d_ws, size_t ws_size,
                              hipStream_t stream) {
  const float* inp = (const float*)d_in[0];   // (N,3,3) f32
  const float* tgt = (const float*)d_in[1];   // (N,3,3) f32
  // d_in[2] = mask (unused by the reference)
  const void* leftp = d_in[3];
  const void* rightp = d_in[4];
  float* out = (float*)d_out;

  const int P = Gg * Ss;                       // 4194304
  const bool idx64 = (in_sizes[3] == 2 * P);   // int64 passthrough guard

  size_t partBytes = (size_t)DIR_BLOCKS * sizeof(float);

  if (!idx64 && ws_size >= partBytes) {
    float* partial = (float*)d_ws;
    fused_kernel<<<PAIR_BLOCKS, PB, 0, stream>>>(
        inp, tgt, (const int*)leftp, (const int*)rightp, partial);
    reduce_kernel<<<1, BLOCK, 0, stream>>>(partial, PAIR_BLOCKS, out);
  } else {
    float* partial = (float*)d_ws;
    if (idx64) {
      pair_kernel_direct<long long><<<DIR_BLOCKS, BLOCK, 0, stream>>>(
          inp, tgt, (const long long*)leftp, (const long long*)rightp, partial);
    } else {
      pair_kernel_direct<int><<<DIR_BLOCKS, BLOCK, 0, stream>>>(
          inp, tgt, (const int*)leftp, (const int*)rightp, partial);
    }
    reduce_kernel<<<1, BLOCK, 0, stream>>>(partial, DIR_BLOCKS, out);
  }
}